// Round 5
// baseline (48194.269 us; speedup 1.0000x reference)
//
#include <hip/hip_runtime.h>
#include <math.h>

#define B_    128
#define T_    256
#define DIM_  512
#define HID_  1024
#define OUT_  512
#define TAG_  64
#define K3_   3072
#define NWG_  96

typedef float f32x4 __attribute__((ext_vector_type(4)));
typedef short bf16x8 __attribute__((ext_vector_type(8)));

#define MFMA(a,b,c) __builtin_amdgcn_mfma_f32_16x16x32_bf16(a,b,c,0,0,0)
#define AT_LD(p)    __hip_atomic_load((p),  __ATOMIC_RELAXED, __HIP_MEMORY_SCOPE_AGENT)
#define AT_ST(p,v)  __hip_atomic_store((p), (v), __ATOMIC_RELAXED, __HIP_MEMORY_SCOPE_AGENT)

__device__ __forceinline__ unsigned short f2b(float f){
    unsigned int u = __float_as_uint(f);
    u = (u + 0x7fffu + ((u >> 16) & 1u)) >> 16;   // RNE
    return (unsigned short)u;
}
__device__ __forceinline__ float hardsig(float x){
    return fminf(fmaxf(0.2f*x + 0.5f, 0.f), 1.f);
}
__device__ __forceinline__ bf16x8 ld8(const unsigned short* p){   // cached 16B
    return *(const bf16x8*)p;
}
__device__ __forceinline__ bf16x8 ld8f(const float* p){           // cached f32 -> bf16
    float4 a = *(const float4*)p;
    float4 b = *(const float4*)(p + 4);
    bf16x8 r;
    r[0]=(short)f2b(a.x); r[1]=(short)f2b(a.y); r[2]=(short)f2b(a.z); r[3]=(short)f2b(a.w);
    r[4]=(short)f2b(b.x); r[5]=(short)f2b(b.y); r[6]=(short)f2b(b.z); r[7]=(short)f2b(b.w);
    return r;
}
// coherent (L2-bypassing) loads/stores for cross-WG data
__device__ __forceinline__ float ldc_f32(const float* p){
    return __uint_as_float(AT_LD((const unsigned*)p));
}
__device__ __forceinline__ void stc_f32(float* p, float v){
    AT_ST((unsigned*)p, __float_as_uint(v));
}
__device__ __forceinline__ bf16x8 ldc_bf16x8(const unsigned short* p){
    const unsigned long long* q = (const unsigned long long*)p;
    union { unsigned long long u[2]; bf16x8 v; } r;
    r.u[0] = AT_LD(q);
    r.u[1] = AT_LD(q + 1);
    return r.v;
}
__device__ __forceinline__ bf16x8 ldc_f32x8_cvt(const float* p){
    const unsigned long long* q = (const unsigned long long*)p;
    unsigned long long a0 = AT_LD(q + 0);
    unsigned long long a1 = AT_LD(q + 1);
    unsigned long long a2 = AT_LD(q + 2);
    unsigned long long a3 = AT_LD(q + 3);
    bf16x8 r;
    r[0]=(short)f2b(__uint_as_float((unsigned)a0)); r[1]=(short)f2b(__uint_as_float((unsigned)(a0>>32)));
    r[2]=(short)f2b(__uint_as_float((unsigned)a1)); r[3]=(short)f2b(__uint_as_float((unsigned)(a1>>32)));
    r[4]=(short)f2b(__uint_as_float((unsigned)a2)); r[5]=(short)f2b(__uint_as_float((unsigned)(a2>>32)));
    r[6]=(short)f2b(__uint_as_float((unsigned)a3)); r[7]=(short)f2b(__uint_as_float((unsigned)(a3>>32)));
    return r;
}

// ---- fence-free grid barrier: all data moves via L2-bypassing atomics, so
// visibility needs only vmcnt(0) (stores completed at coherence point) + flags.
__device__ __forceinline__ void gsync(unsigned* flags, unsigned gen, int wg, int tid){
    __syncthreads();
    asm volatile("s_waitcnt vmcnt(0)" ::: "memory");
    if (tid == 0) AT_ST(&flags[wg], gen);
    if (tid < NWG_){
        while (AT_LD(&flags[tid]) < gen) __builtin_amdgcn_s_sleep(4);
    }
    __syncthreads();
}

// ---------- prep kernels ----------
__global__ __launch_bounds__(256) void k_tr(
    unsigned short* __restrict__ dst, const float* __restrict__ src,
    int K, int ld, int col_off)
{
    __shared__ float tile[32][33];
    const int kb = blockIdx.x * 32, nb = blockIdx.y * 32;
    const int tx = threadIdx.x & 31, ty = threadIdx.x >> 5;
    #pragma unroll
    for (int i = 0; i < 4; ++i){
        int kl = ty + i*8;
        tile[kl][tx] = src[(size_t)(kb + kl)*ld + col_off + nb + tx];
    }
    __syncthreads();
    #pragma unroll
    for (int i = 0; i < 4; ++i){
        int nl = ty + i*8;
        dst[(size_t)(nb + nl)*K + kb + tx] = f2b(tile[tx][nl]);
    }
}
__global__ __launch_bounds__(256) void k_cvtx(
    const float4* __restrict__ src, ushort4* __restrict__ dst, int n4)
{
    int i = blockIdx.x * 256 + threadIdx.x;
    if (i < n4){
        float4 v = src[i];
        ushort4 o;
        o.x = f2b(v.x); o.y = f2b(v.y); o.z = f2b(v.z); o.w = f2b(v.w);
        dst[i] = o;
    }
}
__global__ __launch_bounds__(256) void k_init(
    const float* __restrict__ x0, const float* __restrict__ s0,
    unsigned short* __restrict__ xbuf_b, float* __restrict__ sb0)
{
    int i = blockIdx.x * 256 + threadIdx.x;
    if (i < B_*OUT_) xbuf_b[i] = f2b(x0[i]);
    if (i < B_*HID_) sb0[i] = s0[i];
}

// ================= persistent kernel =================
__global__ __launch_bounds__(512, 1) void k_persist(
    const unsigned short* __restrict__ xb16, const float* __restrict__ xf, int use_xb,
    const unsigned short* __restrict__ Wt,  const unsigned short* __restrict__ Vrt,
    const unsigned short* __restrict__ Vzt, const unsigned short* __restrict__ Vst,
    const unsigned short* __restrict__ Urzt,const unsigned short* __restrict__ Ust,
    const unsigned short* __restrict__ Wxt,
    const float* __restrict__ bias, const float* __restrict__ bx,
    const float* __restrict__ Wy,   const float* __restrict__ by,
    unsigned short* __restrict__ xbuf_b,
    float* __restrict__ rs_f,
    float* __restrict__ sb0, float* __restrict__ sb1,
    float* __restrict__ pre_z, float* __restrict__ pre_xs,
    float* __restrict__ logits,
    float* __restrict__ out, unsigned* __restrict__ flags)
{
    __shared__ float sm_xs[512];
    __shared__ float sm_red[512];
    const int wg   = blockIdx.x;     // 0..95
    const int tid  = threadIdx.x;    // 0..511
    const int lane = tid & 63;
    const int wv   = tid >> 6;       // wave 0..7 (m-tile)
    const int l15  = lane & 15;
    const int kch  = lane >> 4;
    const int arow = wv*16 + l15;
    unsigned gen = 0;

    const int n0A   = wg * 32;
    const int nsegA = n0A >> 10;     // 0=r 1=z 2=xs

    for (int t = 0; t < T_; ++t){
        const float* sp = (t & 1) ? sb1 : sb0;
        float*       sn = (t & 1) ? sb0 : sb1;

        // ===== phase A: pre/rs — 96 WGs x 32 cols =====
        {
            f32x4 acc0 = {0.f,0.f,0.f,0.f}, acc1 = {0.f,0.f,0.f,0.f};
            // seg0: x_tm1 @ W (K=512); xbuf coherent
            {
                const unsigned short* ab = xbuf_b + arow*OUT_ + kch*8;
                const unsigned short* b0 = Wt + (size_t)(n0A + l15)*OUT_ + kch*8;
                const unsigned short* b1 = b0 + 16*OUT_;
                #pragma unroll 4
                for (int kb = 0; kb < OUT_; kb += 32){
                    bf16x8 a = ldc_bf16x8(ab + kb);
                    acc0 = MFMA(a, ld8(b0 + kb), acc0);
                    acc1 = MFMA(a, ld8(b1 + kb), acc1);
                }
            }
            // seg1: inp_t @ V (K=512); input read-only -> cached
            {
                const unsigned short* Vt = (nsegA==0) ? Vrt : ((nsegA==1) ? Vzt : Vst);
                const int nl = n0A - (nsegA << 10);
                const unsigned short* b0 = Vt + (size_t)(nl + l15)*DIM_ + kch*8;
                const unsigned short* b1 = b0 + 16*DIM_;
                if (use_xb){
                    const unsigned short* ab = xb16 + ((size_t)arow*T_ + t)*DIM_ + kch*8;
                    #pragma unroll 4
                    for (int kb = 0; kb < DIM_; kb += 32){
                        bf16x8 a = ld8(ab + kb);
                        acc0 = MFMA(a, ld8(b0 + kb), acc0);
                        acc1 = MFMA(a, ld8(b1 + kb), acc1);
                    }
                } else {
                    const float* af = xf + ((size_t)arow*T_ + t)*DIM_ + kch*8;
                    #pragma unroll 2
                    for (int kb = 0; kb < DIM_; kb += 32){
                        bf16x8 a = ld8f(af + kb);
                        acc0 = MFMA(a, ld8(b0 + kb), acc0);
                        acc1 = MFMA(a, ld8(b1 + kb), acc1);
                    }
                }
            }
            // seg2: s_tm1 @ U_rz (K=1024, r/z only); s coherent f32
            if (nsegA < 2){
                const float* ab = sp + arow*HID_ + kch*8;
                const unsigned short* b0 = Urzt + (size_t)(n0A + l15)*HID_ + kch*8;
                const unsigned short* b1 = b0 + 16*HID_;
                #pragma unroll 4
                for (int kb = 0; kb < HID_; kb += 32){
                    bf16x8 a = ldc_f32x8_cvt(ab + kb);
                    acc0 = MFMA(a, ld8(b0 + kb), acc0);
                    acc1 = MFMA(a, ld8(b1 + kb), acc1);
                }
            }
            const int rbase = wv*16 + kch*4;
            #pragma unroll
            for (int half = 0; half < 2; ++half){
                f32x4 acc = half ? acc1 : acc0;
                const int col = n0A + half*16 + l15;
                const float bv = bias[col];
                #pragma unroll
                for (int q = 0; q < 4; ++q){
                    const int r = rbase + q;
                    const float v = acc[q] + bv;
                    if (nsegA == 0){
                        float rs = hardsig(v) * ldc_f32(&sp[r*HID_ + col]);
                        stc_f32(&rs_f[r*HID_ + col], rs);
                    } else if (nsegA == 1){
                        stc_f32(&pre_z[r*HID_ + col - 1024], v);
                    } else {
                        stc_f32(&pre_xs[r*HID_ + col - 2048], v);
                    }
                }
            }
        }
        gen++; gsync(flags, gen, wg, tid);

        // ===== phase B: s update — 32 WGs x 32 cols, K=1024 =====
        if (wg < 32){
            const int n0 = wg * 32;
            f32x4 acc0 = {0.f,0.f,0.f,0.f}, acc1 = {0.f,0.f,0.f,0.f};
            const float* ab = rs_f + arow*HID_ + kch*8;
            const unsigned short* b0 = Ust + (size_t)(n0 + l15)*HID_ + kch*8;
            const unsigned short* b1 = b0 + 16*HID_;
            #pragma unroll 4
            for (int kb = 0; kb < HID_; kb += 32){
                bf16x8 a = ldc_f32x8_cvt(ab + kb);
                acc0 = MFMA(a, ld8(b0 + kb), acc0);
                acc1 = MFMA(a, ld8(b1 + kb), acc1);
            }
            const int rbase = wv*16 + kch*4;
            #pragma unroll
            for (int half = 0; half < 2; ++half){
                f32x4 acc = half ? acc1 : acc0;
                const int col = n0 + half*16 + l15;
                #pragma unroll
                for (int q = 0; q < 4; ++q){
                    const int r = rbase + q;
                    float z  = hardsig(ldc_f32(&pre_z[r*HID_ + col]));
                    float xs = ldc_f32(&pre_xs[r*HID_ + col]);
                    float so = ldc_f32(&sp[r*HID_ + col]);
                    float s1 = tanhf(xs + acc[q]);
                    stc_f32(&sn[r*HID_ + col], (1.f - z)*so + z*s1);
                }
            }
        }
        gen++; gsync(flags, gen, wg, tid);

        // ===== phase C: logits — 16 WGs x 32 cols, K=1024 =====
        if (wg < 16){
            const int n0 = wg * 32;
            f32x4 acc0 = {0.f,0.f,0.f,0.f}, acc1 = {0.f,0.f,0.f,0.f};
            const float* ab = sn + arow*HID_ + kch*8;
            const unsigned short* b0 = Wxt + (size_t)(n0 + l15)*HID_ + kch*8;
            const unsigned short* b1 = b0 + 16*HID_;
            #pragma unroll 4
            for (int kb = 0; kb < HID_; kb += 32){
                bf16x8 a = ldc_f32x8_cvt(ab + kb);
                acc0 = MFMA(a, ld8(b0 + kb), acc0);
                acc1 = MFMA(a, ld8(b1 + kb), acc1);
            }
            const int rbase = wv*16 + kch*4;
            #pragma unroll
            for (int half = 0; half < 2; ++half){
                f32x4 acc = half ? acc1 : acc0;
                const int col = n0 + half*16 + l15;
                #pragma unroll
                for (int q = 0; q < 4; ++q){
                    stc_f32(&logits[(rbase + q)*OUT_ + col], acc[q] + bx[col]);
                }
            }
        }
        gen++; gsync(flags, gen, wg, tid);

        // ===== phase D: softmax -> x_t ; x_t@Wy -> softmax -> out =====
        for (int r = wg; r < B_; r += NWG_){
            float v = ldc_f32(&logits[r*OUT_ + tid]);
            float m = v;
            #pragma unroll
            for (int off = 32; off > 0; off >>= 1) m = fmaxf(m, __shfl_xor(m, off));
            if (lane == 0) sm_red[wv] = m;
            __syncthreads();
            float mx = sm_red[0];
            #pragma unroll
            for (int q = 1; q < 8; ++q) mx = fmaxf(mx, sm_red[q]);
            float e = expf(v - mx);
            float ssum = e;
            #pragma unroll
            for (int off = 32; off > 0; off >>= 1) ssum += __shfl_xor(ssum, off);
            __syncthreads();
            if (lane == 0) sm_red[wv] = ssum;
            __syncthreads();
            float tot = 0.f;
            #pragma unroll
            for (int q = 0; q < 8; ++q) tot += sm_red[q];
            float xv = e / tot;
            sm_xs[tid] = xv;
            __syncthreads();
            if (tid < 256){
                unsigned pk = ((unsigned)f2b(sm_xs[2*tid+1]) << 16) | (unsigned)f2b(sm_xs[2*tid]);
                AT_ST((unsigned*)xbuf_b + r*256 + tid, pk);
            }
            const int tag = tid & 63, part = tid >> 6;
            float p = 0.f;
            const int k0 = part * 64;
            #pragma unroll 4
            for (int k = k0; k < k0 + 64; ++k) p += sm_xs[k] * Wy[k*TAG_ + tag];
            sm_red[tid] = p;
            __syncthreads();
            if (tid < 64){
                float tl = by[tid];
                #pragma unroll
                for (int q = 0; q < 8; ++q) tl += sm_red[q*64 + tid];
                float wm = tl;
                #pragma unroll
                for (int off = 32; off > 0; off >>= 1) wm = fmaxf(wm, __shfl_xor(wm, off));
                float ex = expf(tl - wm);
                float sm = ex;
                #pragma unroll
                for (int off = 32; off > 0; off >>= 1) sm += __shfl_xor(sm, off);
                out[((long)r*T_ + t)*TAG_ + tid] = ex / sm;
            }
            __syncthreads();
        }
        gen++; gsync(flags, gen, wg, tid);
    }
}

extern "C" void kernel_launch(void* const* d_in, const int* in_sizes, int n_in,
                              void* d_out, int out_size, void* d_ws, size_t ws_size,
                              hipStream_t stream){
    const float* x   = (const float*)d_in[0];
    const float* x0  = (const float*)d_in[1];
    const float* s0  = (const float*)d_in[2];
    const float* W   = (const float*)d_in[3];
    const float* U   = (const float*)d_in[4];
    const float* b   = (const float*)d_in[5];
    const float* Wx  = (const float*)d_in[6];
    const float* bx  = (const float*)d_in[7];
    const float* Vr  = (const float*)d_in[8];
    const float* Vz  = (const float*)d_in[9];
    const float* Vs  = (const float*)d_in[10];
    const float* Wy  = (const float*)d_in[11];
    const float* by  = (const float*)d_in[12];
    float* out = (float*)d_out;

    char* ws = (char*)d_ws;
    size_t off = 0;
    auto alloc = [&](size_t bytes) -> size_t {
        size_t o = off; off = (off + bytes + 255) & ~(size_t)255; return o;
    };
    unsigned* flags       = (unsigned*)(ws + alloc(512));
    unsigned short* Wt    = (unsigned short*)(ws + alloc((size_t)K3_*OUT_*2));
    unsigned short* Urzt  = (unsigned short*)(ws + alloc((size_t)2048*HID_*2));
    unsigned short* Ust   = (unsigned short*)(ws + alloc((size_t)HID_*HID_*2));
    unsigned short* Vrt   = (unsigned short*)(ws + alloc((size_t)HID_*DIM_*2));
    unsigned short* Vzt   = (unsigned short*)(ws + alloc((size_t)HID_*DIM_*2));
    unsigned short* Vst   = (unsigned short*)(ws + alloc((size_t)HID_*DIM_*2));
    unsigned short* Wxt   = (unsigned short*)(ws + alloc((size_t)OUT_*HID_*2));
    unsigned short* xbuf_b= (unsigned short*)(ws + alloc((size_t)B_*OUT_*2));
    float* rs_f   = (float*)(ws + alloc((size_t)B_*HID_*4));
    float* sb0    = (float*)(ws + alloc((size_t)B_*HID_*4));
    float* sb1    = (float*)(ws + alloc((size_t)B_*HID_*4));
    float* pre_z  = (float*)(ws + alloc((size_t)B_*HID_*4));
    float* pre_xs = (float*)(ws + alloc((size_t)B_*HID_*4));
    float* logits = (float*)(ws + alloc((size_t)B_*OUT_*4));
    unsigned short* xb16 = (unsigned short*)(ws + alloc((size_t)B_*T_*DIM_*2));
    int use_xb = (off <= ws_size) ? 1 : 0;

    hipMemsetAsync(flags, 0, 512, stream);
    k_tr<<<dim3(OUT_/32, K3_/32),  256, 0, stream>>>(Wt,   W,  OUT_, K3_, 0);
    k_tr<<<dim3(HID_/32, 2048/32), 256, 0, stream>>>(Urzt, U,  HID_, K3_, 0);
    k_tr<<<dim3(HID_/32, HID_/32), 256, 0, stream>>>(Ust,  U,  HID_, K3_, 2048);
    k_tr<<<dim3(DIM_/32, HID_/32), 256, 0, stream>>>(Vrt,  Vr, DIM_, HID_, 0);
    k_tr<<<dim3(DIM_/32, HID_/32), 256, 0, stream>>>(Vzt,  Vz, DIM_, HID_, 0);
    k_tr<<<dim3(DIM_/32, HID_/32), 256, 0, stream>>>(Vst,  Vs, DIM_, HID_, 0);
    k_tr<<<dim3(HID_/32, OUT_/32), 256, 0, stream>>>(Wxt,  Wx, HID_, OUT_, 0);
    if (use_xb){
        int n4 = B_*T_*DIM_/4;
        k_cvtx<<<(n4 + 255)/256, 256, 0, stream>>>((const float4*)x, (ushort4*)xb16, n4);
    }
    k_init<<<(B_*HID_ + 255)/256, 256, 0, stream>>>(x0, s0, xbuf_b, sb0);

    const unsigned short* xb16c = xb16;
    void* kargs[] = {
        (void*)&xb16c, (void*)&x, (void*)&use_xb,
        (void*)&Wt, (void*)&Vrt, (void*)&Vzt, (void*)&Vst, (void*)&Urzt, (void*)&Ust,
        (void*)&Wxt, (void*)&b, (void*)&bx, (void*)&Wy, (void*)&by,
        (void*)&xbuf_b, (void*)&rs_f, (void*)&sb0, (void*)&sb1,
        (void*)&pre_z, (void*)&pre_xs, (void*)&logits,
        (void*)&out, (void*)&flags
    };
    hipError_t err = hipLaunchCooperativeKernel((const void*)k_persist,
                                                dim3(NWG_), dim3(512),
                                                kargs, 0, stream);
    if (err != hipSuccess){
        // 96 WGs, 512 thr, ~4KB LDS: trivially co-resident on 256 CUs.
        k_persist<<<NWG_, 512, 0, stream>>>(
            xb16c, x, use_xb, Wt, Vrt, Vzt, Vst, Urzt, Ust, Wxt,
            b, bx, Wy, by, xbuf_b, rs_f, sb0, sb1, pre_z, pre_xs, logits, out, flags);
    }
}

// Round 7
// 47295.697 us; speedup vs baseline: 1.0190x; 1.0190x over previous
//
#include <hip/hip_runtime.h>
#include <math.h>

#define B_    128
#define T_    256
#define DIM_  512
#define HID_  1024
#define OUT_  512
#define TAG_  64
#define K3_   3072
#define NWG_  96

typedef float f32x4 __attribute__((ext_vector_type(4)));
typedef short bf16x8 __attribute__((ext_vector_type(8)));
typedef unsigned uint32x4 __attribute__((ext_vector_type(4)));

#define MFMA(a,b,c) __builtin_amdgcn_mfma_f32_16x16x32_bf16(a,b,c,0,0,0)
#define DRAINV do{ asm volatile("s_waitcnt vmcnt(0)" ::: "memory"); __builtin_amdgcn_sched_barrier(0); }while(0)

__device__ __forceinline__ unsigned short f2b(float f){
    unsigned int u = __float_as_uint(f);
    u = (u + 0x7fffu + ((u >> 16) & 1u)) >> 16;   // RNE
    return (unsigned short)u;
}
__device__ __forceinline__ float hardsig(float x){
    return fminf(fmaxf(0.2f*x + 0.5f, 0.f), 1.f);
}

// ---- coherent (L3 / coherence-point) ops: sc0 sc1 on BOTH loads and stores ----
__device__ __forceinline__ uint32x4 ldco16(const void* p){
    uint32x4 r;
    asm volatile("global_load_dwordx4 %0, %1, off sc0 sc1" : "=v"(r) : "v"(p));
    return r;
}
__device__ __forceinline__ float ldcof(const float* p){
    float r;
    asm volatile("global_load_dword %0, %1, off sc0 sc1" : "=v"(r) : "v"(p));
    return r;
}
__device__ __forceinline__ unsigned ldcou_wait(const unsigned* p){
    unsigned r;
    asm volatile("global_load_dword %0, %1, off sc0 sc1\n\ts_waitcnt vmcnt(0)"
                 : "=v"(r) : "v"(p) : "memory");
    return r;
}
__device__ __forceinline__ void stcou(unsigned* p, unsigned v){
    asm volatile("global_store_dword %0, %1, off sc0 sc1" :: "v"(p), "v"(v) : "memory");
}
__device__ __forceinline__ void stcof(float* p, float v){
    asm volatile("global_store_dword %0, %1, off sc0 sc1" :: "v"(p), "v"(v) : "memory");
}
__device__ __forceinline__ void stco16b(unsigned short* p, unsigned short v){
    unsigned vv = v;
    asm volatile("global_store_short %0, %1, off sc0 sc1" :: "v"(p), "v"(vv) : "memory");
}
__device__ __forceinline__ uint32x4 pack8f(const float* p){
    float4 a = *(const float4*)p;
    float4 b = *(const float4*)(p + 4);
    uint32x4 r;
    r.x = ((unsigned)f2b(a.y) << 16) | f2b(a.x);
    r.y = ((unsigned)f2b(a.w) << 16) | f2b(a.z);
    r.z = ((unsigned)f2b(b.y) << 16) | f2b(b.x);
    r.w = ((unsigned)f2b(b.w) << 16) | f2b(b.z);
    return r;
}

// ---- grid barrier: distributed flags, sc0sc1 both sides, no fences ----
__device__ __forceinline__ void gbar(unsigned* flags, unsigned gen, int wg, int tid){
    DRAINV;                 // my coherent stores reached the coherence point
    __syncthreads();        // all threads in WG drained
    if (tid == 0) stcou(&flags[wg], gen);
    if (tid < NWG_){
        while (ldcou_wait(&flags[tid]) < gen) __builtin_amdgcn_s_sleep(8);
    }
    __syncthreads();
}

// ---------- prep kernels ----------
__global__ __launch_bounds__(256) void k_tr(
    unsigned short* __restrict__ dst, int dstride,
    const float* __restrict__ src, int ld, int col_off)
{
    __shared__ float tile[32][33];
    const int kb = blockIdx.x * 32, nb = blockIdx.y * 32;
    const int tx = threadIdx.x & 31, ty = threadIdx.x >> 5;
    #pragma unroll
    for (int i = 0; i < 4; ++i){
        int kl = ty + i*8;
        tile[kl][tx] = src[(size_t)(kb + kl)*ld + col_off + nb + tx];
    }
    __syncthreads();
    #pragma unroll
    for (int i = 0; i < 4; ++i){
        int nl = ty + i*8;
        dst[(size_t)(nb + nl)*dstride + kb + tx] = f2b(tile[tx][nl]);
    }
}
__global__ __launch_bounds__(256) void k_cvtx(
    const float4* __restrict__ src, ushort4* __restrict__ dst, int n4)
{
    int i = blockIdx.x * 256 + threadIdx.x;
    if (i < n4){
        float4 v = src[i];
        ushort4 o;
        o.x = f2b(v.x); o.y = f2b(v.y); o.z = f2b(v.z); o.w = f2b(v.w);
        dst[i] = o;
    }
}
__global__ __launch_bounds__(256) void k_init(
    const float* __restrict__ x0, const float* __restrict__ s0,
    unsigned short* __restrict__ xbufB, float* __restrict__ s_f,
    unsigned short* __restrict__ s_b)
{
    int i = blockIdx.x * 256 + threadIdx.x;
    if (i < B_*OUT_) xbufB[i] = f2b(x0[i]);
    if (i < B_*HID_){ s_f[i] = s0[i]; s_b[i] = f2b(s0[i]); }
}

// ---- staged GEMM over K=1024, 4 chunks of 256 (phases B and C) ----
__device__ __forceinline__ void gemm_k1024(
    char* smem, int tid, int arow, int kch,
    const unsigned short* src, const unsigned short* bp0,
    f32x4& acc0, f32x4& acc1)
{
    const unsigned short* bp1 = bp0 + (size_t)16*1024;
    const int asw = arow & 7;
    uint32x4 sv[8];
    #pragma unroll
    for (int j = 0; j < 8; ++j){
        int i = tid + j*512;
        sv[j] = ldco16(src + (i>>5)*1024 + (i&31)*8);
    }
    DRAINV;
    #pragma unroll
    for (int j = 0; j < 8; ++j){
        int i = tid + j*512; int row = i>>5, k16 = i&31;
        *(uint32x4*)(smem + row*512 + ((k16 ^ (row&7))<<4)) = sv[j];
    }
    __syncthreads();
    int cur = 0;
    for (int c = 0; c < 4; ++c){
        if (c < 3){
            #pragma unroll
            for (int j = 0; j < 8; ++j){
                int i = tid + j*512;
                sv[j] = ldco16(src + (i>>5)*1024 + (c+1)*256 + (i&31)*8);
            }
        }
        const unsigned short* bc0 = bp0 + c*256;
        const unsigned short* bc1 = bp1 + c*256;
        const int abase = (cur ? 65536 : 0) + arow*512;
        #pragma unroll
        for (int kk = 0; kk < 256; kk += 32){
            bf16x8 a = *(const bf16x8*)(smem + abase + ((((kk>>3)+kch) ^ asw)<<4));
            acc0 = MFMA(a, *(const bf16x8*)(bc0+kk), acc0);
            acc1 = MFMA(a, *(const bf16x8*)(bc1+kk), acc1);
        }
        DRAINV;
        if (c < 3){
            const int nb = (cur^1) ? 65536 : 0;
            #pragma unroll
            for (int j = 0; j < 8; ++j){
                int i = tid + j*512; int row = i>>5, k16 = i&31;
                *(uint32x4*)(smem + nb + row*512 + ((k16 ^ (row&7))<<4)) = sv[j];
            }
        }
        __syncthreads();
        cur ^= 1;
    }
}

// ================= persistent kernel =================
__global__ __launch_bounds__(512, 1) void k_persist(
    const unsigned short* __restrict__ xb16, const float* __restrict__ xf, int use_xb,
    const unsigned short* __restrict__ Wcat, const unsigned short* __restrict__ Ust,
    const unsigned short* __restrict__ Wxt,
    const float* __restrict__ bias, const float* __restrict__ bx,
    const float* __restrict__ Wy,   const float* __restrict__ by,
    unsigned short* __restrict__ xbufB, unsigned short* __restrict__ s_bb,
    unsigned short* __restrict__ rs_bb, float* __restrict__ s_f,
    float* __restrict__ pre_z, float* __restrict__ pre_xs,
    float* __restrict__ logits, float* __restrict__ out,
    unsigned* __restrict__ flags)
{
    __shared__ __align__(16) char smem[131072];
    __shared__ float sm_xs[512];
    __shared__ float sm_red[512];

    const int wg   = blockIdx.x;      // 0..95
    const int tid  = threadIdx.x;     // 0..511
    const int lane = tid & 63;
    const int wv   = tid >> 6;        // wave 0..7 = m-tile
    const int l15  = lane & 15;
    const int kch  = lane >> 4;
    const int arow = wv*16 + l15;
    const int asw  = arow & 7;
    const int rbase = wv*16 + kch*4;
    unsigned gen = 0;

    const int n0A   = wg * 32;
    const int nsegA = n0A >> 10;      // 0=r 1=z 2=xs

    for (int t = 0; t < T_; ++t){
        const float* spf = s_f + (size_t)(t & 1)*(B_*HID_);
        float*       snf = s_f + (size_t)((t & 1)^1)*(B_*HID_);

        // ===== phase A: pre/rs — 96 WGs x 32 cols, K = 2048 (r/z) / 1024 (xs) =====
        {
            const int cnum = (nsegA < 2) ? 8 : 4;
            const unsigned short* bp0 = Wcat + (size_t)(n0A + l15)*2048 + (kch<<3);
            const unsigned short* bp1 = bp0 + (size_t)16*2048;
            f32x4 acc0 = {0.f,0.f,0.f,0.f}, acc1 = {0.f,0.f,0.f,0.f};
            uint32x4 sv[8];
            auto issueA = [&](int c){
                #pragma unroll
                for (int j = 0; j < 8; ++j){
                    const int i = tid + j*512;
                    const int row = i>>5, k16 = i&31;
                    if (c < 2)       sv[j] = ldco16(xbufB + row*512 + c*256 + k16*8);
                    else if (c < 4){
                        if (use_xb)  sv[j] = ldco16(xb16 + ((size_t)row*T_ + t)*DIM_ + (c-2)*256 + k16*8);
                        else         sv[j] = pack8f(xf + ((size_t)row*T_ + t)*DIM_ + (c-2)*256 + k16*8);
                    } else           sv[j] = ldco16(s_bb + row*1024 + (c-4)*256 + k16*8);
                }
            };
            auto writeSV = [&](int boff){
                #pragma unroll
                for (int j = 0; j < 8; ++j){
                    const int i = tid + j*512;
                    const int row = i>>5, k16 = i&31;
                    *(uint32x4*)(smem + boff + row*512 + ((k16 ^ (row&7))<<4)) = sv[j];
                }
            };
            issueA(0); DRAINV; writeSV(0); __syncthreads();
            int cur = 0;
            for (int c = 0; c < cnum; ++c){
                if (c + 1 < cnum) issueA(c+1);
                const unsigned short* bc0 = bp0 + c*256;
                const unsigned short* bc1 = bp1 + c*256;
                const int abase = (cur ? 65536 : 0) + arow*512;
                #pragma unroll
                for (int kk = 0; kk < 256; kk += 32){
                    bf16x8 a = *(const bf16x8*)(smem + abase + ((((kk>>3)+kch) ^ asw)<<4));
                    acc0 = MFMA(a, *(const bf16x8*)(bc0+kk), acc0);
                    acc1 = MFMA(a, *(const bf16x8*)(bc1+kk), acc1);
                }
                DRAINV;
                if (c + 1 < cnum) writeSV((cur^1) ? 65536 : 0);
                __syncthreads();
                cur ^= 1;
            }
            // epilogue
            if (nsegA == 0){
                float sold[8];
                #pragma unroll
                for (int h = 0; h < 2; ++h){
                    const int col = n0A + h*16 + l15;
                    #pragma unroll
                    for (int q = 0; q < 4; ++q)
                        sold[h*4+q] = ldcof(spf + (size_t)(rbase+q)*1024 + col);
                }
                DRAINV;
                #pragma unroll
                for (int h = 0; h < 2; ++h){
                    f32x4 acc = h ? acc1 : acc0;
                    const int col = n0A + h*16 + l15;
                    const float bv = bias[col];
                    #pragma unroll
                    for (int q = 0; q < 4; ++q){
                        float rs = hardsig(acc[q] + bv) * sold[h*4+q];
                        stco16b(rs_bb + (size_t)(rbase+q)*1024 + col, f2b(rs));
                    }
                }
            } else {
                float* dst = (nsegA == 1) ? pre_z : pre_xs;
                const int coff = (nsegA == 1) ? 1024 : 2048;
                #pragma unroll
                for (int h = 0; h < 2; ++h){
                    f32x4 acc = h ? acc1 : acc0;
                    const int col = n0A + h*16 + l15;
                    const float bv = bias[col];
                    #pragma unroll
                    for (int q = 0; q < 4; ++q)
                        stcof(dst + (size_t)(rbase+q)*1024 + (col - coff), acc[q] + bv);
                }
            }
        }
        ++gen; gbar(flags, gen, wg, tid);

        // ===== phase B: s update — 32 WGs x 32 cols, K=1024 =====
        if (wg < 32){
            const int n0 = wg * 32;
            f32x4 acc0 = {0.f,0.f,0.f,0.f}, acc1 = {0.f,0.f,0.f,0.f};
            gemm_k1024(smem, tid, arow, kch, rs_bb,
                       Ust + (size_t)(n0 + l15)*1024 + (kch<<3), acc0, acc1);
            float pz[8], px[8], so[8];
            #pragma unroll
            for (int h = 0; h < 2; ++h){
                const int col = n0 + h*16 + l15;
                #pragma unroll
                for (int q = 0; q < 4; ++q){
                    const size_t idx = (size_t)(rbase+q)*1024 + col;
                    pz[h*4+q] = ldcof(pre_z  + idx);
                    px[h*4+q] = ldcof(pre_xs + idx);
                    so[h*4+q] = ldcof(spf    + idx);
                }
            }
            DRAINV;
            #pragma unroll
            for (int h = 0; h < 2; ++h){
                f32x4 acc = h ? acc1 : acc0;
                const int col = n0 + h*16 + l15;
                #pragma unroll
                for (int q = 0; q < 4; ++q){
                    const size_t idx = (size_t)(rbase+q)*1024 + col;
                    float z  = hardsig(pz[h*4+q]);
                    float s1 = tanhf(px[h*4+q] + acc[q]);
                    float sv = (1.f - z)*so[h*4+q] + z*s1;
                    stcof(snf + idx, sv);
                    stco16b(s_bb + idx, f2b(sv));
                }
            }
        }
        ++gen; gbar(flags, gen, wg, tid);

        // ===== phase C: logits — 16 WGs x 32 cols, K=1024 =====
        if (wg < 16){
            const int n0 = wg * 32;
            f32x4 acc0 = {0.f,0.f,0.f,0.f}, acc1 = {0.f,0.f,0.f,0.f};
            gemm_k1024(smem, tid, arow, kch, s_bb,
                       Wxt + (size_t)(n0 + l15)*1024 + (kch<<3), acc0, acc1);
            #pragma unroll
            for (int h = 0; h < 2; ++h){
                f32x4 acc = h ? acc1 : acc0;
                const int col = n0 + h*16 + l15;
                const float bv = bx[col];
                #pragma unroll
                for (int q = 0; q < 4; ++q)
                    stcof(logits + (size_t)(rbase+q)*512 + col, acc[q] + bv);
            }
        }
        ++gen; gbar(flags, gen, wg, tid);

        // ===== phase D: softmax -> x_t ; x_t@Wy -> softmax -> out =====
        for (int r = wg; r < B_; r += NWG_){
            float v;
            {
                unsigned u;
                asm volatile("global_load_dword %0, %1, off sc0 sc1"
                             : "=v"(u) : "v"(logits + r*512 + tid));
                DRAINV;
                v = __uint_as_float(u);
            }
            float m = v;
            #pragma unroll
            for (int off = 32; off > 0; off >>= 1) m = fmaxf(m, __shfl_xor(m, off));
            if (lane == 0) sm_red[wv] = m;
            __syncthreads();
            float mx = sm_red[0];
            #pragma unroll
            for (int q = 1; q < 8; ++q) mx = fmaxf(mx, sm_red[q]);
            float e = expf(v - mx);
            float ssum = e;
            #pragma unroll
            for (int off = 32; off > 0; off >>= 1) ssum += __shfl_xor(ssum, off);
            __syncthreads();
            if (lane == 0) sm_red[wv] = ssum;
            __syncthreads();
            float tot = 0.f;
            #pragma unroll
            for (int q = 0; q < 8; ++q) tot += sm_red[q];
            float xv = e / tot;
            sm_xs[tid] = xv;
            __syncthreads();
            if (tid < 256){
                unsigned pk = ((unsigned)f2b(sm_xs[2*tid+1]) << 16) | (unsigned)f2b(sm_xs[2*tid]);
                stcou((unsigned*)xbufB + r*256 + tid, pk);
            }
            const int tag = tid & 63, part = tid >> 6;
            float p = 0.f;
            const int k0 = part * 64;
            #pragma unroll 4
            for (int kk = k0; kk < k0 + 64; ++kk) p += sm_xs[kk] * Wy[kk*TAG_ + tag];
            sm_red[tid] = p;
            __syncthreads();
            if (tid < 64){
                float tl = by[tid];
                #pragma unroll
                for (int q = 0; q < 8; ++q) tl += sm_red[q*64 + tid];
                float wm = tl;
                #pragma unroll
                for (int off = 32; off > 0; off >>= 1) wm = fmaxf(wm, __shfl_xor(wm, off));
                float ex = expf(tl - wm);
                float sm = ex;
                #pragma unroll
                for (int off = 32; off > 0; off >>= 1) sm += __shfl_xor(sm, off);
                out[((size_t)r*T_ + t)*TAG_ + tid] = ex / sm;
            }
            __syncthreads();
        }
        ++gen; gbar(flags, gen, wg, tid);
    }
}

extern "C" void kernel_launch(void* const* d_in, const int* in_sizes, int n_in,
                              void* d_out, int out_size, void* d_ws, size_t ws_size,
                              hipStream_t stream){
    const float* x   = (const float*)d_in[0];
    const float* x0  = (const float*)d_in[1];
    const float* s0  = (const float*)d_in[2];
    const float* W   = (const float*)d_in[3];
    const float* U   = (const float*)d_in[4];
    const float* b   = (const float*)d_in[5];
    const float* Wx  = (const float*)d_in[6];
    const float* bx  = (const float*)d_in[7];
    const float* Vr  = (const float*)d_in[8];
    const float* Vz  = (const float*)d_in[9];
    const float* Vs  = (const float*)d_in[10];
    const float* Wy  = (const float*)d_in[11];
    const float* by  = (const float*)d_in[12];
    float* out = (float*)d_out;

    char* ws = (char*)d_ws;
    size_t off = 0;
    auto alloc = [&](size_t bytes) -> size_t {
        size_t o = off; off = (off + bytes + 255) & ~(size_t)255; return o;
    };
    unsigned* flags      = (unsigned*)(ws + alloc(4096));
    unsigned short* Wcat = (unsigned short*)(ws + alloc((size_t)K3_*2048*2));
    unsigned short* Ust  = (unsigned short*)(ws + alloc((size_t)HID_*HID_*2));
    unsigned short* Wxt  = (unsigned short*)(ws + alloc((size_t)OUT_*HID_*2));
    unsigned short* xbufB= (unsigned short*)(ws + alloc((size_t)B_*OUT_*2));
    unsigned short* s_b  = (unsigned short*)(ws + alloc((size_t)B_*HID_*2));
    unsigned short* rs_b = (unsigned short*)(ws + alloc((size_t)B_*HID_*2));
    float* s_f    = (float*)(ws + alloc((size_t)2*B_*HID_*4));
    float* pre_z  = (float*)(ws + alloc((size_t)B_*HID_*4));
    float* pre_xs = (float*)(ws + alloc((size_t)B_*HID_*4));
    float* logits = (float*)(ws + alloc((size_t)B_*OUT_*4));
    unsigned short* xb16 = (unsigned short*)(ws + alloc((size_t)B_*T_*DIM_*2));
    int use_xb = (off <= ws_size) ? 1 : 0;

    hipMemsetAsync(flags, 0, 4096, stream);
    // Wcat[col][2048]: k 0..511 = W; 512..1023 = V{r,z,s} by section; 1024..2047 = U_rz (cols<2048)
    k_tr<<<dim3(16, 96), 256, 0, stream>>>(Wcat,                           2048, W,  K3_,  0);
    k_tr<<<dim3(16, 32), 256, 0, stream>>>(Wcat + 512,                     2048, Vr, HID_, 0);
    k_tr<<<dim3(16, 32), 256, 0, stream>>>(Wcat + (size_t)1024*2048 + 512, 2048, Vz, HID_, 0);
    k_tr<<<dim3(16, 32), 256, 0, stream>>>(Wcat + (size_t)2048*2048 + 512, 2048, Vs, HID_, 0);
    k_tr<<<dim3(32, 64), 256, 0, stream>>>(Wcat + 1024,                    2048, U,  K3_,  0);
    k_tr<<<dim3(32, 32), 256, 0, stream>>>(Ust,                            1024, U,  K3_,  2048);
    k_tr<<<dim3(32, 16), 256, 0, stream>>>(Wxt,                            1024, Wx, OUT_, 0);
    if (use_xb){
        int n4 = B_*T_*DIM_/4;
        k_cvtx<<<(n4 + 255)/256, 256, 0, stream>>>((const float4*)x, (ushort4*)xb16, n4);
    }
    k_init<<<(B_*HID_ + 255)/256, 256, 0, stream>>>(x0, s0, xbufB, s_f, s_b);

    const unsigned short* xb16c = xb16;
    void* kargs[] = {
        (void*)&xb16c, (void*)&x, (void*)&use_xb,
        (void*)&Wcat, (void*)&Ust, (void*)&Wxt,
        (void*)&b, (void*)&bx, (void*)&Wy, (void*)&by,
        (void*)&xbufB, (void*)&s_b, (void*)&rs_b, (void*)&s_f,
        (void*)&pre_z, (void*)&pre_xs, (void*)&logits,
        (void*)&out, (void*)&flags
    };
    hipError_t err = hipLaunchCooperativeKernel((const void*)k_persist,
                                                dim3(NWG_), dim3(512),
                                                kargs, 0, stream);
    if (err != hipSuccess){
        // 96 WGs x 512 thr, 132KB LDS -> 1 WG/CU; 96 <= 256 CUs: co-resident by capacity.
        k_persist<<<NWG_, 512, 0, stream>>>(
            xb16c, x, use_xb, Wcat, Ust, Wxt, b, bx, Wy, by,
            xbufB, s_b, rs_b, s_f, pre_z, pre_xs, logits, out, flags);
    }
}

// Round 9
// 29517.413 us; speedup vs baseline: 1.6327x; 1.6023x over previous
//
#include <hip/hip_runtime.h>
#include <math.h>

#define B_    128
#define T_    256
#define DIM_  512
#define HID_  1024
#define OUT_  512
#define TAG_  64
#define K3_   3072
#define NWG_  96

typedef float f32x4 __attribute__((ext_vector_type(4)));
typedef short bf16x8 __attribute__((ext_vector_type(8)));
typedef unsigned uint32x4 __attribute__((ext_vector_type(4)));

#define MFMA(a,b,c) __builtin_amdgcn_mfma_f32_16x16x32_bf16(a,b,c,0,0,0)
#define DRAINV do{ asm volatile("s_waitcnt vmcnt(0)" ::: "memory"); __builtin_amdgcn_sched_barrier(0); }while(0)

__device__ __forceinline__ unsigned short f2b(float f){
    unsigned int u = __float_as_uint(f);
    u = (u + 0x7fffu + ((u >> 16) & 1u)) >> 16;   // RNE
    return (unsigned short)u;
}
__device__ __forceinline__ float hardsig(float x){
    return fminf(fmaxf(0.2f*x + 0.5f, 0.f), 1.f);
}

// ---- coherence-point ops: sc0 sc1 on BOTH loads and stores (r7-proven) ----
__device__ __forceinline__ uint32x4 ldco16(const void* p){
    uint32x4 r;
    asm volatile("global_load_dwordx4 %0, %1, off sc0 sc1" : "=v"(r) : "v"(p));
    return r;
}
__device__ __forceinline__ float ldcof(const float* p){
    float r;
    asm volatile("global_load_dword %0, %1, off sc0 sc1" : "=v"(r) : "v"(p));
    return r;
}
__device__ __forceinline__ unsigned ldcou_wait(const unsigned* p){
    unsigned r;
    asm volatile("global_load_dword %0, %1, off sc0 sc1\n\ts_waitcnt vmcnt(0)"
                 : "=v"(r) : "v"(p) : "memory");
    return r;
}
__device__ __forceinline__ void stcou(unsigned* p, unsigned v){
    asm volatile("global_store_dword %0, %1, off sc0 sc1" :: "v"(p), "v"(v) : "memory");
}
__device__ __forceinline__ void stcof(float* p, float v){
    asm volatile("global_store_dword %0, %1, off sc0 sc1" :: "v"(p), "v"(v) : "memory");
}
__device__ __forceinline__ void stco16b(unsigned short* p, unsigned short v){
    unsigned vv = v;
    asm volatile("global_store_short %0, %1, off sc0 sc1" :: "v"(p), "v"(vv) : "memory");
}
__device__ __forceinline__ uint32x4 pack8f(const float* p){
    float4 a = *(const float4*)p;
    float4 b = *(const float4*)(p + 4);
    uint32x4 r;
    r.x = ((unsigned)f2b(a.y) << 16) | f2b(a.x);
    r.y = ((unsigned)f2b(a.w) << 16) | f2b(a.z);
    r.z = ((unsigned)f2b(b.y) << 16) | f2b(b.x);
    r.w = ((unsigned)f2b(b.w) << 16) | f2b(b.z);
    return r;
}

// ---- two-level grid barrier: relaxed fetch-add arrive + single go-word ----
// All data moves sc0sc1 (coherence point), so visibility needs only vmcnt(0)
// before arrival. tid0-only poll with sleep backoff kills the poll storm.
__device__ __forceinline__ void gbar2(unsigned* cnt, unsigned* go, unsigned gen, int tid){
    DRAINV;
    __syncthreads();
    if (tid == 0){
        unsigned old = __hip_atomic_fetch_add(cnt, 1u, __ATOMIC_RELAXED, __HIP_MEMORY_SCOPE_AGENT);
        if (old == gen*NWG_ - 1u){
            stcou(go, gen);
        } else {
            while (ldcou_wait(go) < gen) __builtin_amdgcn_s_sleep(8);
        }
    }
    __syncthreads();
}

// ---------- prep kernels ----------
__global__ __launch_bounds__(256) void k_tr(
    unsigned short* __restrict__ dst, int dstride,
    const float* __restrict__ src, int ld, int col_off)
{
    __shared__ float tile[32][33];
    const int kb = blockIdx.x * 32, nb = blockIdx.y * 32;
    const int tx = threadIdx.x & 31, ty = threadIdx.x >> 5;
    #pragma unroll
    for (int i = 0; i < 4; ++i){
        int kl = ty + i*8;
        tile[kl][tx] = src[(size_t)(kb + kl)*ld + col_off + nb + tx];
    }
    __syncthreads();
    #pragma unroll
    for (int i = 0; i < 4; ++i){
        int nl = ty + i*8;
        dst[(size_t)(nb + nl)*dstride + kb + tx] = f2b(tile[tx][nl]);
    }
}
__global__ __launch_bounds__(256) void k_cvtx(
    const float4* __restrict__ src, ushort4* __restrict__ dst, int n4)
{
    int i = blockIdx.x * 256 + threadIdx.x;
    if (i < n4){
        float4 v = src[i];
        ushort4 o;
        o.x = f2b(v.x); o.y = f2b(v.y); o.z = f2b(v.z); o.w = f2b(v.w);
        dst[i] = o;
    }
}
__global__ __launch_bounds__(256) void k_init(
    const float* __restrict__ x0, const float* __restrict__ s0,
    unsigned short* __restrict__ xbufB, float* __restrict__ s_f,
    unsigned short* __restrict__ s_b)
{
    int i = blockIdx.x * 256 + threadIdx.x;
    if (i < B_*OUT_) xbufB[i] = f2b(x0[i]);
    if (i < B_*HID_){ s_f[i] = s0[i]; s_b[i] = f2b(s0[i]); }
}

// ================= persistent kernel =================
__global__ __launch_bounds__(512, 1) void k_persist(
    const unsigned short* __restrict__ xb16, const float* __restrict__ xf, int use_xb,
    const unsigned short* __restrict__ Wcat, const unsigned short* __restrict__ Ust,
    const unsigned short* __restrict__ Wxt,
    const float* __restrict__ bias, const float* __restrict__ bx,
    const float* __restrict__ Wy,   const float* __restrict__ by,
    unsigned short* __restrict__ xbufB, unsigned short* __restrict__ s_bb,
    unsigned short* __restrict__ rs_bb, float* __restrict__ s_f,
    float* __restrict__ pre_z, float* __restrict__ pre_xs,
    float* __restrict__ logits, float* __restrict__ out,
    unsigned* __restrict__ cnt, unsigned* __restrict__ go)
{
    __shared__ __align__(16) char smem[131072];
    __shared__ float sm_xs[512];
    __shared__ float sm_red[512];

    const int wg   = blockIdx.x;      // 0..95
    const int tid  = threadIdx.x;     // 0..511
    const int lane = tid & 63;
    const int wv   = tid >> 6;        // 0..7
    const int l15  = lane & 15;
    const int kch  = lane >> 4;
    const int mt   = wv >> 2;         // wave m-tile 0..1
    const int ns   = wv & 3;          // wave n-sub 0..3
    const int axor = l15 & 7;

    // phase A mapping: 4 M-parts x 24 N-strips of 128 cols
    const int mpA = wg & 3,  npA = wg >> 2;
    const int m0A = mpA*32,  cA = npA*128, nsegA = npA >> 3;  // 0=r 1=z 2=xs
    unsigned gen = 0;

    for (int t = 0; t < T_; ++t){
        const float* spf = s_f + (size_t)(t & 1)*(B_*HID_);
        float*       snf = s_f + (size_t)((t & 1)^1)*(B_*HID_);

        // ===== phase A: pre/rs =====
        {
            if (nsegA < 2){          // stage 32 rows x 2048 K (xbuf|x|s)
                uint32x4 sv[16];
                #pragma unroll
                for (int j = 0; j < 16; ++j){
                    const int c = tid + j*512, row = c >> 8, k16 = c & 255;
                    const int gr = m0A + row;
                    if (k16 < 64)       sv[j] = ldco16(xbufB + gr*512 + k16*8);
                    else if (k16 < 128){
                        if (use_xb)     sv[j] = *(const uint32x4*)(xb16 + ((size_t)gr*T_ + t)*DIM_ + (k16-64)*8);
                        else            sv[j] = pack8f(xf + ((size_t)gr*T_ + t)*DIM_ + (k16-64)*8);
                    } else              sv[j] = ldco16(s_bb + gr*1024 + (k16-128)*8);
                }
                DRAINV;
                #pragma unroll
                for (int j = 0; j < 16; ++j){
                    const int c = tid + j*512, row = c >> 8, k16 = c & 255;
                    *(uint32x4*)(smem + row*4096 + ((k16 ^ (row & 7)) << 4)) = sv[j];
                }
            } else {                 // stage 32 rows x 1024 K (xbuf|x)
                uint32x4 sv[8];
                #pragma unroll
                for (int j = 0; j < 8; ++j){
                    const int c = tid + j*512, row = c >> 7, k16 = c & 127;
                    const int gr = m0A + row;
                    if (k16 < 64)       sv[j] = ldco16(xbufB + gr*512 + k16*8);
                    else {
                        if (use_xb)     sv[j] = *(const uint32x4*)(xb16 + ((size_t)gr*T_ + t)*DIM_ + (k16-64)*8);
                        else            sv[j] = pack8f(xf + ((size_t)gr*T_ + t)*DIM_ + (k16-64)*8);
                    }
                }
                DRAINV;
                #pragma unroll
                for (int j = 0; j < 8; ++j){
                    const int c = tid + j*512, row = c >> 7, k16 = c & 127;
                    *(uint32x4*)(smem + row*4096 + ((k16 ^ (row & 7)) << 4)) = sv[j];
                }
            }
            __syncthreads();

            const int c0 = cA + ns*32;
            const int kmax = (nsegA < 2) ? 2048 : 1024;
            const unsigned short* bp0 = Wcat + (size_t)(c0 + l15)*2048 + kch*8;
            const unsigned short* bp1 = bp0 + (size_t)16*2048;
            f32x4 acc0 = {0.f,0.f,0.f,0.f}, acc1 = {0.f,0.f,0.f,0.f};
            const int abase = (mt*16 + l15)*4096;
            #pragma unroll 8
            for (int kb = 0; kb < kmax; kb += 32){
                bf16x8 a = *(const bf16x8*)(smem + abase + ((((kb>>3)+kch) ^ axor) << 4));
                acc0 = MFMA(a, *(const bf16x8*)(bp0 + kb), acc0);
                acc1 = MFMA(a, *(const bf16x8*)(bp1 + kb), acc1);
            }
            const int rbA = m0A + mt*16 + kch*4;
            if (nsegA == 0){
                float sold[8];
                #pragma unroll
                for (int h = 0; h < 2; ++h){
                    const int col = c0 + h*16 + l15;
                    #pragma unroll
                    for (int q = 0; q < 4; ++q)
                        sold[h*4+q] = ldcof(spf + (size_t)(rbA+q)*1024 + col);
                }
                DRAINV;
                #pragma unroll
                for (int h = 0; h < 2; ++h){
                    f32x4 acc = h ? acc1 : acc0;
                    const int col = c0 + h*16 + l15;
                    const float bv = bias[col];
                    #pragma unroll
                    for (int q = 0; q < 4; ++q){
                        float rs = hardsig(acc[q] + bv) * sold[h*4+q];
                        stco16b(rs_bb + (size_t)(rbA+q)*1024 + col, f2b(rs));
                    }
                }
            } else if (nsegA == 1){
                #pragma unroll
                for (int h = 0; h < 2; ++h){
                    f32x4 acc = h ? acc1 : acc0;
                    const int col = c0 + h*16 + l15;
                    const float bv = bias[col];
                    #pragma unroll
                    for (int q = 0; q < 4; ++q)
                        stcof(pre_z + (size_t)(rbA+q)*1024 + (col - 1024), acc[q] + bv);
                }
            } else {
                #pragma unroll
                for (int h = 0; h < 2; ++h){
                    f32x4 acc = h ? acc1 : acc0;
                    const int col = c0 + h*16 + l15;
                    const float bv = bias[col];
                    #pragma unroll
                    for (int q = 0; q < 4; ++q)
                        stcof(pre_xs + (size_t)(rbA+q)*1024 + (col - 2048), acc[q] + bv);
                }
            }
        }
        ++gen; gbar2(cnt, go, gen, tid);

        // ===== phase B: s update — 32 WGs (4 Mp x 8 Np), K=1024 =====
        if (wg < 32){
            const int m0B = (wg & 3)*32, cB = (wg >> 2)*128;
            {
                uint32x4 sv[8];
                #pragma unroll
                for (int j = 0; j < 8; ++j){
                    const int c = tid + j*512, row = c >> 7, k16 = c & 127;
                    sv[j] = ldco16(rs_bb + (size_t)(m0B+row)*1024 + k16*8);
                }
                DRAINV;
                #pragma unroll
                for (int j = 0; j < 8; ++j){
                    const int c = tid + j*512, row = c >> 7, k16 = c & 127;
                    *(uint32x4*)(smem + row*2048 + ((k16 ^ (row & 7)) << 4)) = sv[j];
                }
            }
            __syncthreads();
            const int c0 = cB + ns*32;
            const unsigned short* bp0 = Ust + (size_t)(c0 + l15)*1024 + kch*8;
            const unsigned short* bp1 = bp0 + (size_t)16*1024;
            f32x4 acc0 = {0.f,0.f,0.f,0.f}, acc1 = {0.f,0.f,0.f,0.f};
            const int abase = (mt*16 + l15)*2048;
            #pragma unroll 8
            for (int kb = 0; kb < 1024; kb += 32){
                bf16x8 a = *(const bf16x8*)(smem + abase + ((((kb>>3)+kch) ^ axor) << 4));
                acc0 = MFMA(a, *(const bf16x8*)(bp0 + kb), acc0);
                acc1 = MFMA(a, *(const bf16x8*)(bp1 + kb), acc1);
            }
            const int rbB = m0B + mt*16 + kch*4;
            float pz[8], px[8], so[8];
            #pragma unroll
            for (int h = 0; h < 2; ++h){
                const int col = c0 + h*16 + l15;
                #pragma unroll
                for (int q = 0; q < 4; ++q){
                    const size_t idx = (size_t)(rbB+q)*1024 + col;
                    pz[h*4+q] = ldcof(pre_z  + idx);
                    px[h*4+q] = ldcof(pre_xs + idx);
                    so[h*4+q] = ldcof(spf    + idx);
                }
            }
            DRAINV;
            #pragma unroll
            for (int h = 0; h < 2; ++h){
                f32x4 acc = h ? acc1 : acc0;
                const int col = c0 + h*16 + l15;
                #pragma unroll
                for (int q = 0; q < 4; ++q){
                    const size_t idx = (size_t)(rbB+q)*1024 + col;
                    float z  = hardsig(pz[h*4+q]);
                    float sv2 = (1.f - z)*so[h*4+q] + z*tanhf(px[h*4+q] + acc[q]);
                    stcof(snf + idx, sv2);
                    stco16b(s_bb + idx, f2b(sv2));
                }
            }
        }
        ++gen; gbar2(cnt, go, gen, tid);

        // ===== phase C: logits — 16 WGs (4 Mp x 4 Np), K=1024 =====
        if (wg < 16){
            const int m0C = (wg & 3)*32, cC = (wg >> 2)*128;
            {
                uint32x4 sv[8];
                #pragma unroll
                for (int j = 0; j < 8; ++j){
                    const int c = tid + j*512, row = c >> 7, k16 = c & 127;
                    sv[j] = ldco16(s_bb + (size_t)(m0C+row)*1024 + k16*8);
                }
                DRAINV;
                #pragma unroll
                for (int j = 0; j < 8; ++j){
                    const int c = tid + j*512, row = c >> 7, k16 = c & 127;
                    *(uint32x4*)(smem + row*2048 + ((k16 ^ (row & 7)) << 4)) = sv[j];
                }
            }
            __syncthreads();
            const int c0 = cC + ns*32;
            const unsigned short* bp0 = Wxt + (size_t)(c0 + l15)*1024 + kch*8;
            const unsigned short* bp1 = bp0 + (size_t)16*1024;
            f32x4 acc0 = {0.f,0.f,0.f,0.f}, acc1 = {0.f,0.f,0.f,0.f};
            const int abase = (mt*16 + l15)*2048;
            #pragma unroll 8
            for (int kb = 0; kb < 1024; kb += 32){
                bf16x8 a = *(const bf16x8*)(smem + abase + ((((kb>>3)+kch) ^ axor) << 4));
                acc0 = MFMA(a, *(const bf16x8*)(bp0 + kb), acc0);
                acc1 = MFMA(a, *(const bf16x8*)(bp1 + kb), acc1);
            }
            const int rbC = m0C + mt*16 + kch*4;
            #pragma unroll
            for (int h = 0; h < 2; ++h){
                f32x4 acc = h ? acc1 : acc0;
                const int col = c0 + h*16 + l15;
                const float bv = bx[col];
                #pragma unroll
                for (int q = 0; q < 4; ++q)
                    stcof(logits + (size_t)(rbC+q)*512 + col, acc[q] + bv);
            }
        }
        ++gen; gbar2(cnt, go, gen, tid);

        // ===== phase D: softmax -> x_t ; x_t@Wy -> softmax -> out =====
        for (int r = wg; r < B_; r += NWG_){
            float v = ldcof(logits + (size_t)r*512 + tid);
            DRAINV;
            float m = v;
            #pragma unroll
            for (int off = 32; off > 0; off >>= 1) m = fmaxf(m, __shfl_xor(m, off));
            if (lane == 0) sm_red[wv] = m;
            __syncthreads();
            float mx = sm_red[0];
            #pragma unroll
            for (int q = 1; q < 8; ++q) mx = fmaxf(mx, sm_red[q]);
            float e = expf(v - mx);
            float ssum = e;
            #pragma unroll
            for (int off = 32; off > 0; off >>= 1) ssum += __shfl_xor(ssum, off);
            __syncthreads();
            if (lane == 0) sm_red[wv] = ssum;
            __syncthreads();
            float tot = 0.f;
            #pragma unroll
            for (int q = 0; q < 8; ++q) tot += sm_red[q];
            float xv = e / tot;
            sm_xs[tid] = xv;
            __syncthreads();
            if (tid < 256){
                unsigned pk = ((unsigned)f2b(sm_xs[2*tid+1]) << 16) | (unsigned)f2b(sm_xs[2*tid]);
                stcou((unsigned*)xbufB + r*256 + tid, pk);
            }
            const int tag = tid & 63, part = tid >> 6;
            float p = 0.f;
            const int k0 = part * 64;
            #pragma unroll 4
            for (int kk = k0; kk < k0 + 64; ++kk) p += sm_xs[kk] * Wy[kk*TAG_ + tag];
            sm_red[tid] = p;
            __syncthreads();
            if (tid < 64){
                float tl = by[tid];
                #pragma unroll
                for (int q = 0; q < 8; ++q) tl += sm_red[q*64 + tid];
                float wm = tl;
                #pragma unroll
                for (int off = 32; off > 0; off >>= 1) wm = fmaxf(wm, __shfl_xor(wm, off));
                float ex = expf(tl - wm);
                float sm = ex;
                #pragma unroll
                for (int off = 32; off > 0; off >>= 1) sm += __shfl_xor(sm, off);
                out[((size_t)r*T_ + t)*TAG_ + tid] = ex / sm;
            }
            __syncthreads();
        }
        ++gen; gbar2(cnt, go, gen, tid);
    }
}

extern "C" void kernel_launch(void* const* d_in, const int* in_sizes, int n_in,
                              void* d_out, int out_size, void* d_ws, size_t ws_size,
                              hipStream_t stream){
    const float* x   = (const float*)d_in[0];
    const float* x0  = (const float*)d_in[1];
    const float* s0  = (const float*)d_in[2];
    const float* W   = (const float*)d_in[3];
    const float* U   = (const float*)d_in[4];
    const float* b   = (const float*)d_in[5];
    const float* Wx  = (const float*)d_in[6];
    const float* bx  = (const float*)d_in[7];
    const float* Vr  = (const float*)d_in[8];
    const float* Vz  = (const float*)d_in[9];
    const float* Vs  = (const float*)d_in[10];
    const float* Wy  = (const float*)d_in[11];
    const float* by  = (const float*)d_in[12];
    float* out = (float*)d_out;

    char* ws = (char*)d_ws;
    size_t off = 0;
    auto alloc = [&](size_t bytes) -> size_t {
        size_t o = off; off = (off + bytes + 255) & ~(size_t)255; return o;
    };
    unsigned* ctrl = (unsigned*)(ws + alloc(4096));
    unsigned* cnt  = ctrl;            // arrival counter (monotonic)
    unsigned* go   = ctrl + 64;       // go word, separate line
    unsigned short* Wcat = (unsigned short*)(ws + alloc((size_t)K3_*2048*2));
    unsigned short* Ust  = (unsigned short*)(ws + alloc((size_t)HID_*HID_*2));
    unsigned short* Wxt  = (unsigned short*)(ws + alloc((size_t)OUT_*HID_*2));
    unsigned short* xbufB= (unsigned short*)(ws + alloc((size_t)B_*OUT_*2));
    unsigned short* s_b  = (unsigned short*)(ws + alloc((size_t)B_*HID_*2));
    unsigned short* rs_b = (unsigned short*)(ws + alloc((size_t)B_*HID_*2));
    float* s_f    = (float*)(ws + alloc((size_t)2*B_*HID_*4));
    float* pre_z  = (float*)(ws + alloc((size_t)B_*HID_*4));
    float* pre_xs = (float*)(ws + alloc((size_t)B_*HID_*4));
    float* logits = (float*)(ws + alloc((size_t)B_*OUT_*4));
    unsigned short* xb16 = (unsigned short*)(ws + alloc((size_t)B_*T_*DIM_*2));
    int use_xb = (off <= ws_size) ? 1 : 0;

    hipMemsetAsync(ctrl, 0, 4096, stream);
    // Wcat[col][2048]: k 0..511 = W; 512..1023 = V{r,z,s} by col-section; 1024..2047 = U_rz (cols<2048)
    k_tr<<<dim3(16, 96), 256, 0, stream>>>(Wcat,                           2048, W,  K3_,  0);
    k_tr<<<dim3(16, 32), 256, 0, stream>>>(Wcat + 512,                     2048, Vr, HID_, 0);
    k_tr<<<dim3(16, 32), 256, 0, stream>>>(Wcat + (size_t)1024*2048 + 512, 2048, Vz, HID_, 0);
    k_tr<<<dim3(16, 32), 256, 0, stream>>>(Wcat + (size_t)2048*2048 + 512, 2048, Vs, HID_, 0);
    k_tr<<<dim3(32, 64), 256, 0, stream>>>(Wcat + 1024,                    2048, U,  K3_,  0);
    k_tr<<<dim3(32, 32), 256, 0, stream>>>(Ust,                            1024, U,  K3_,  2048);
    k_tr<<<dim3(32, 16), 256, 0, stream>>>(Wxt,                            1024, Wx, OUT_, 0);
    if (use_xb){
        int n4 = B_*T_*DIM_/4;
        k_cvtx<<<(n4 + 255)/256, 256, 0, stream>>>((const float4*)x, (ushort4*)xb16, n4);
    }
    k_init<<<(B_*HID_ + 255)/256, 256, 0, stream>>>(x0, s0, xbufB, s_f, s_b);

    const unsigned short* xb16c = xb16;
    void* kargs[] = {
        (void*)&xb16c, (void*)&x, (void*)&use_xb,
        (void*)&Wcat, (void*)&Ust, (void*)&Wxt,
        (void*)&b, (void*)&bx, (void*)&Wy, (void*)&by,
        (void*)&xbufB, (void*)&s_b, (void*)&rs_b, (void*)&s_f,
        (void*)&pre_z, (void*)&pre_xs, (void*)&logits,
        (void*)&out, (void*)&cnt, (void*)&go
    };
    hipError_t err = hipLaunchCooperativeKernel((const void*)k_persist,
                                                dim3(NWG_), dim3(512),
                                                kargs, 0, stream);
    if (err != hipSuccess){
        // 96 WGs x 512 thr x 132KB LDS -> 1 WG/CU; 96 <= 256 CUs: co-resident.
        k_persist<<<NWG_, 512, 0, stream>>>(
            xb16c, x, use_xb, Wcat, Ust, Wxt, b, bx, Wy, by,
            xbufB, s_b, rs_b, s_f, pre_z, pre_xs, logits, out, cnt, go);
    }
}

// Round 10
// 19730.063 us; speedup vs baseline: 2.4427x; 1.4961x over previous
//
#include <hip/hip_runtime.h>
#include <math.h>

#define B_    128
#define T_    256
#define DIM_  512
#define HID_  1024
#define OUT_  512
#define TAG_  64
#define K3_   3072

typedef float f32x4 __attribute__((ext_vector_type(4)));
typedef short bf16x8 __attribute__((ext_vector_type(8)));
typedef unsigned uint32x4 __attribute__((ext_vector_type(4)));

#define MFMA(a,b,c) __builtin_amdgcn_mfma_f32_16x16x32_bf16(a,b,c,0,0,0)
#define DRAINV do{ asm volatile("s_waitcnt vmcnt(0)" ::: "memory"); __builtin_amdgcn_sched_barrier(0); }while(0)

__device__ __forceinline__ unsigned short f2b(float f){
    unsigned int u = __float_as_uint(f);
    u = (u + 0x7fffu + ((u >> 16) & 1u)) >> 16;   // RNE
    return (unsigned short)u;
}
__device__ __forceinline__ float hardsig(float x){
    return fminf(fmaxf(0.2f*x + 0.5f, 0.f), 1.f);
}
__device__ __forceinline__ uint32x4 ld16(const void* p){
    return *(const uint32x4*)p;
}
__device__ __forceinline__ uint32x4 pack8f(const float* p){
    float4 a = *(const float4*)p;
    float4 b = *(const float4*)(p + 4);
    uint32x4 r;
    r.x = ((unsigned)f2b(a.y) << 16) | f2b(a.x);
    r.y = ((unsigned)f2b(a.w) << 16) | f2b(a.z);
    r.z = ((unsigned)f2b(b.y) << 16) | f2b(b.x);
    r.w = ((unsigned)f2b(b.w) << 16) | f2b(b.z);
    return r;
}

// ---------- prep kernels ----------
__global__ __launch_bounds__(256) void k_tr(
    unsigned short* __restrict__ dst, int dstride,
    const float* __restrict__ src, int ld, int col_off)
{
    __shared__ float tile[32][33];
    const int kb = blockIdx.x * 32, nb = blockIdx.y * 32;
    const int tx = threadIdx.x & 31, ty = threadIdx.x >> 5;
    #pragma unroll
    for (int i = 0; i < 4; ++i){
        int kl = ty + i*8;
        tile[kl][tx] = src[(size_t)(kb + kl)*ld + col_off + nb + tx];
    }
    __syncthreads();
    #pragma unroll
    for (int i = 0; i < 4; ++i){
        int nl = ty + i*8;
        dst[(size_t)(nb + nl)*dstride + kb + tx] = f2b(tile[tx][nl]);
    }
}
__global__ __launch_bounds__(256) void k_cvtx(
    const float4* __restrict__ src, ushort4* __restrict__ dst, int n4)
{
    int i = blockIdx.x * 256 + threadIdx.x;
    if (i < n4){
        float4 v = src[i];
        ushort4 o;
        o.x = f2b(v.x); o.y = f2b(v.y); o.z = f2b(v.z); o.w = f2b(v.w);
        dst[i] = o;
    }
}
__global__ __launch_bounds__(256) void k_init(
    const float* __restrict__ x0, const float* __restrict__ s0,
    unsigned short* __restrict__ xbufB, float* __restrict__ s_f,
    unsigned short* __restrict__ s_b)
{
    int i = blockIdx.x * 256 + threadIdx.x;
    if (i < B_*OUT_) xbufB[i] = f2b(x0[i]);
    if (i < B_*HID_){ s_f[i] = s0[i]; s_b[i] = f2b(s0[i]); }
}

// ===== phase A: pre/rs — 96 WGs: np (strip of 128 cols) = wg%24, mp = wg/24 =====
// strip-major => XCD = wg%8 = np%8: 3 weight strips/XCD (~1.3MB) stay L2-resident.
__global__ __launch_bounds__(512) void k_gA(
    const unsigned short* __restrict__ xb16, const float* __restrict__ xf, int use_xb,
    const unsigned short* __restrict__ Wcat, const float* __restrict__ bias,
    const unsigned short* __restrict__ xbufB, const unsigned short* __restrict__ s_bb,
    const float* __restrict__ spf,
    unsigned short* __restrict__ rs_bb, float* __restrict__ pre_z,
    float* __restrict__ pre_xs, int t)
{
    __shared__ __align__(16) char smem[131072];
    const int wg   = blockIdx.x;
    const int tid  = threadIdx.x;
    const int lane = tid & 63;
    const int wv   = tid >> 6;
    const int l15  = lane & 15;
    const int kch  = lane >> 4;
    const int mt   = wv >> 2;         // 0..1
    const int ns   = wv & 3;          // 0..3
    const int axor = l15 & 7;

    const int npA = wg % 24, mpA = wg / 24;
    const int m0A = mpA*32, cA = npA*128, nsegA = npA >> 3;   // 0=r 1=z 2=xs

    if (nsegA < 2){          // stage 32 rows x 2048 K (xbuf|x|s)
        #pragma unroll
        for (int j = 0; j < 16; ++j){
            const int c = tid + j*512, row = c >> 8, k16 = c & 255;
            const int gr = m0A + row;
            uint32x4 v;
            if (k16 < 64)       v = ld16(xbufB + gr*512 + k16*8);
            else if (k16 < 128){
                if (use_xb)     v = ld16(xb16 + ((size_t)gr*T_ + t)*DIM_ + (k16-64)*8);
                else            v = pack8f(xf + ((size_t)gr*T_ + t)*DIM_ + (k16-64)*8);
            } else              v = ld16(s_bb + gr*1024 + (k16-128)*8);
            *(uint32x4*)(smem + row*4096 + ((k16 ^ (row & 7)) << 4)) = v;
        }
    } else {                 // stage 32 rows x 1024 K (xbuf|x)
        #pragma unroll
        for (int j = 0; j < 8; ++j){
            const int c = tid + j*512, row = c >> 7, k16 = c & 127;
            const int gr = m0A + row;
            uint32x4 v;
            if (k16 < 64)       v = ld16(xbufB + gr*512 + k16*8);
            else {
                if (use_xb)     v = ld16(xb16 + ((size_t)gr*T_ + t)*DIM_ + (k16-64)*8);
                else            v = pack8f(xf + ((size_t)gr*T_ + t)*DIM_ + (k16-64)*8);
            }
            *(uint32x4*)(smem + row*4096 + ((k16 ^ (row & 7)) << 4)) = v;
        }
    }
    __syncthreads();

    const int c0 = cA + ns*32;
    const int kmax = (nsegA < 2) ? 2048 : 1024;
    const unsigned short* bp0 = Wcat + (size_t)(c0 + l15)*2048 + kch*8;
    const unsigned short* bp1 = bp0 + (size_t)16*2048;
    f32x4 acc0 = {0.f,0.f,0.f,0.f}, acc1 = {0.f,0.f,0.f,0.f};
    const int abase = (mt*16 + l15)*4096;
    #pragma unroll 8
    for (int kb = 0; kb < kmax; kb += 32){
        bf16x8 a = *(const bf16x8*)(smem + abase + ((((kb>>3)+kch) ^ axor) << 4));
        acc0 = MFMA(a, *(const bf16x8*)(bp0 + kb), acc0);
        acc1 = MFMA(a, *(const bf16x8*)(bp1 + kb), acc1);
    }
    const int rbA = m0A + mt*16 + kch*4;
    if (nsegA == 0){
        #pragma unroll
        for (int h = 0; h < 2; ++h){
            f32x4 acc = h ? acc1 : acc0;
            const int col = c0 + h*16 + l15;
            const float bv = bias[col];
            #pragma unroll
            for (int q = 0; q < 4; ++q){
                float rs = hardsig(acc[q] + bv) * spf[(size_t)(rbA+q)*1024 + col];
                rs_bb[(size_t)(rbA+q)*1024 + col] = f2b(rs);
            }
        }
    } else if (nsegA == 1){
        #pragma unroll
        for (int h = 0; h < 2; ++h){
            f32x4 acc = h ? acc1 : acc0;
            const int col = c0 + h*16 + l15;
            const float bv = bias[col];
            #pragma unroll
            for (int q = 0; q < 4; ++q)
                pre_z[(size_t)(rbA+q)*1024 + (col - 1024)] = acc[q] + bv;
        }
    } else {
        #pragma unroll
        for (int h = 0; h < 2; ++h){
            f32x4 acc = h ? acc1 : acc0;
            const int col = c0 + h*16 + l15;
            const float bv = bias[col];
            #pragma unroll
            for (int q = 0; q < 4; ++q)
                pre_xs[(size_t)(rbA+q)*1024 + (col - 2048)] = acc[q] + bv;
        }
    }
}

// ===== phase B: s update — 32 WGs: np = wg%8 (128-col strip), mp = wg/8 =====
__global__ __launch_bounds__(512) void k_gB(
    const unsigned short* __restrict__ Ust,
    const unsigned short* __restrict__ rs_bb,
    const float* __restrict__ pre_z, const float* __restrict__ pre_xs,
    const float* __restrict__ spf,
    float* __restrict__ snf, unsigned short* __restrict__ s_bb)
{
    __shared__ __align__(16) char smem[65536];
    const int wg   = blockIdx.x;
    const int tid  = threadIdx.x;
    const int lane = tid & 63;
    const int wv   = tid >> 6;
    const int l15  = lane & 15;
    const int kch  = lane >> 4;
    const int mt   = wv >> 2;
    const int ns   = wv & 3;
    const int axor = l15 & 7;
    const int np = wg % 8, mp = wg / 8;
    const int m0B = mp*32, cB = np*128;

    #pragma unroll
    for (int j = 0; j < 8; ++j){
        const int c = tid + j*512, row = c >> 7, k16 = c & 127;
        uint32x4 v = ld16(rs_bb + (size_t)(m0B+row)*1024 + k16*8);
        *(uint32x4*)(smem + row*2048 + ((k16 ^ (row & 7)) << 4)) = v;
    }
    __syncthreads();

    const int c0 = cB + ns*32;
    const unsigned short* bp0 = Ust + (size_t)(c0 + l15)*1024 + kch*8;
    const unsigned short* bp1 = bp0 + (size_t)16*1024;
    f32x4 acc0 = {0.f,0.f,0.f,0.f}, acc1 = {0.f,0.f,0.f,0.f};
    const int abase = (mt*16 + l15)*2048;
    #pragma unroll 8
    for (int kb = 0; kb < 1024; kb += 32){
        bf16x8 a = *(const bf16x8*)(smem + abase + ((((kb>>3)+kch) ^ axor) << 4));
        acc0 = MFMA(a, *(const bf16x8*)(bp0 + kb), acc0);
        acc1 = MFMA(a, *(const bf16x8*)(bp1 + kb), acc1);
    }
    const int rbB = m0B + mt*16 + kch*4;
    #pragma unroll
    for (int h = 0; h < 2; ++h){
        f32x4 acc = h ? acc1 : acc0;
        const int col = c0 + h*16 + l15;
        #pragma unroll
        for (int q = 0; q < 4; ++q){
            const size_t idx = (size_t)(rbB+q)*1024 + col;
            float z  = hardsig(pre_z[idx]);
            float sv = (1.f - z)*spf[idx] + z*tanhf(pre_xs[idx] + acc[q]);
            snf[idx]  = sv;
            s_bb[idx] = f2b(sv);
        }
    }
}

// ===== phase C: logits — 16 WGs: np = wg%4 (128-col strip), mp = wg/4 =====
__global__ __launch_bounds__(512) void k_gC(
    const unsigned short* __restrict__ Wxt,
    const unsigned short* __restrict__ s_bb,
    const float* __restrict__ bx, float* __restrict__ logits)
{
    __shared__ __align__(16) char smem[65536];
    const int wg   = blockIdx.x;
    const int tid  = threadIdx.x;
    const int lane = tid & 63;
    const int wv   = tid >> 6;
    const int l15  = lane & 15;
    const int kch  = lane >> 4;
    const int mt   = wv >> 2;
    const int ns   = wv & 3;
    const int axor = l15 & 7;
    const int np = wg % 4, mp = wg / 4;
    const int m0C = mp*32, cC = np*128;

    #pragma unroll
    for (int j = 0; j < 8; ++j){
        const int c = tid + j*512, row = c >> 7, k16 = c & 127;
        uint32x4 v = ld16(s_bb + (size_t)(m0C+row)*1024 + k16*8);
        *(uint32x4*)(smem + row*2048 + ((k16 ^ (row & 7)) << 4)) = v;
    }
    __syncthreads();

    const int c0 = cC + ns*32;
    const unsigned short* bp0 = Wxt + (size_t)(c0 + l15)*1024 + kch*8;
    const unsigned short* bp1 = bp0 + (size_t)16*1024;
    f32x4 acc0 = {0.f,0.f,0.f,0.f}, acc1 = {0.f,0.f,0.f,0.f};
    const int abase = (mt*16 + l15)*2048;
    #pragma unroll 8
    for (int kb = 0; kb < 1024; kb += 32){
        bf16x8 a = *(const bf16x8*)(smem + abase + ((((kb>>3)+kch) ^ axor) << 4));
        acc0 = MFMA(a, *(const bf16x8*)(bp0 + kb), acc0);
        acc1 = MFMA(a, *(const bf16x8*)(bp1 + kb), acc1);
    }
    const int rbC = m0C + mt*16 + kch*4;
    #pragma unroll
    for (int h = 0; h < 2; ++h){
        f32x4 acc = h ? acc1 : acc0;
        const int col = c0 + h*16 + l15;
        const float bv = bx[col];
        #pragma unroll
        for (int q = 0; q < 4; ++q)
            logits[(size_t)(rbC+q)*512 + col] = acc[q] + bv;
    }
}

// ===== phase D: softmax -> x_t ; x_t@Wy -> softmax -> out (128 WGs x 256) =====
__global__ __launch_bounds__(256) void k_soft(
    const float* __restrict__ logits, const float* __restrict__ Wy,
    const float* __restrict__ by, unsigned short* __restrict__ xbufB,
    float* __restrict__ out, int t)
{
    __shared__ float xs[512];
    __shared__ float red[256];
    const int r = blockIdx.x, tid = threadIdx.x;
    float v0 = logits[r*OUT_ + tid];
    float v1 = logits[r*OUT_ + 256 + tid];
    red[tid] = fmaxf(v0, v1);
    __syncthreads();
    for (int s = 128; s > 0; s >>= 1){
        if (tid < s) red[tid] = fmaxf(red[tid], red[tid+s]);
        __syncthreads();
    }
    float mx = red[0];
    __syncthreads();
    float e0 = expf(v0 - mx), e1 = expf(v1 - mx);
    red[tid] = e0 + e1;
    __syncthreads();
    for (int s = 128; s > 0; s >>= 1){
        if (tid < s) red[tid] += red[tid+s];
        __syncthreads();
    }
    float inv = 1.f / red[0];
    __syncthreads();
    float x0v = e0*inv, x1v = e1*inv;
    xs[tid] = x0v; xs[tid + 256] = x1v;
    xbufB[r*OUT_ + tid] = f2b(x0v);
    xbufB[r*OUT_ + 256 + tid] = f2b(x1v);
    __syncthreads();
    const int j = tid & 63, part = tid >> 6;
    float p = 0.f;
    const int k0 = part * 128;
    #pragma unroll 4
    for (int k = k0; k < k0 + 128; ++k) p += xs[k] * Wy[k*TAG_ + j];
    red[tid] = p;
    __syncthreads();
    if (tid < 64){
        float tl = red[tid] + red[tid+64] + red[tid+128] + red[tid+192] + by[tid];
        float wm = tl;
        #pragma unroll
        for (int off = 32; off > 0; off >>= 1) wm = fmaxf(wm, __shfl_xor(wm, off));
        float ex = expf(tl - wm);
        float sm = ex;
        #pragma unroll
        for (int off = 32; off > 0; off >>= 1) sm += __shfl_xor(sm, off);
        out[((long)r*T_ + t)*TAG_ + tid] = ex / sm;
    }
}

extern "C" void kernel_launch(void* const* d_in, const int* in_sizes, int n_in,
                              void* d_out, int out_size, void* d_ws, size_t ws_size,
                              hipStream_t stream){
    const float* x   = (const float*)d_in[0];
    const float* x0  = (const float*)d_in[1];
    const float* s0  = (const float*)d_in[2];
    const float* W   = (const float*)d_in[3];
    const float* U   = (const float*)d_in[4];
    const float* b   = (const float*)d_in[5];
    const float* Wx  = (const float*)d_in[6];
    const float* bx  = (const float*)d_in[7];
    const float* Vr  = (const float*)d_in[8];
    const float* Vz  = (const float*)d_in[9];
    const float* Vs  = (const float*)d_in[10];
    const float* Wy  = (const float*)d_in[11];
    const float* by  = (const float*)d_in[12];
    float* out = (float*)d_out;

    char* ws = (char*)d_ws;
    size_t off = 0;
    auto alloc = [&](size_t bytes) -> size_t {
        size_t o = off; off = (off + bytes + 255) & ~(size_t)255; return o;
    };
    unsigned short* Wcat = (unsigned short*)(ws + alloc((size_t)K3_*2048*2));
    unsigned short* Ust  = (unsigned short*)(ws + alloc((size_t)HID_*HID_*2));
    unsigned short* Wxt  = (unsigned short*)(ws + alloc((size_t)OUT_*HID_*2));
    unsigned short* xbufB= (unsigned short*)(ws + alloc((size_t)B_*OUT_*2));
    unsigned short* s_b  = (unsigned short*)(ws + alloc((size_t)B_*HID_*2));
    unsigned short* rs_b = (unsigned short*)(ws + alloc((size_t)B_*HID_*2));
    float* s_f    = (float*)(ws + alloc((size_t)2*B_*HID_*4));
    float* pre_z  = (float*)(ws + alloc((size_t)B_*HID_*4));
    float* pre_xs = (float*)(ws + alloc((size_t)B_*HID_*4));
    float* logits = (float*)(ws + alloc((size_t)B_*OUT_*4));
    unsigned short* xb16 = (unsigned short*)(ws + alloc((size_t)B_*T_*DIM_*2));
    int use_xb = (off <= ws_size) ? 1 : 0;

    // Wcat[col][2048]: k 0..511 = W; 512..1023 = V{r,z,s} by col-section; 1024..2047 = U_rz (cols<2048)
    k_tr<<<dim3(16, 96), 256, 0, stream>>>(Wcat,                           2048, W,  K3_,  0);
    k_tr<<<dim3(16, 32), 256, 0, stream>>>(Wcat + 512,                     2048, Vr, HID_, 0);
    k_tr<<<dim3(16, 32), 256, 0, stream>>>(Wcat + (size_t)1024*2048 + 512, 2048, Vz, HID_, 0);
    k_tr<<<dim3(16, 32), 256, 0, stream>>>(Wcat + (size_t)2048*2048 + 512, 2048, Vs, HID_, 0);
    k_tr<<<dim3(32, 64), 256, 0, stream>>>(Wcat + 1024,                    2048, U,  K3_,  0);
    k_tr<<<dim3(32, 32), 256, 0, stream>>>(Ust,                            1024, U,  K3_,  2048);
    k_tr<<<dim3(32, 16), 256, 0, stream>>>(Wxt,                            1024, Wx, OUT_, 0);
    if (use_xb){
        int n4 = B_*T_*DIM_/4;
        k_cvtx<<<(n4 + 255)/256, 256, 0, stream>>>((const float4*)x, (ushort4*)xb16, n4);
    }
    k_init<<<(B_*HID_ + 255)/256, 256, 0, stream>>>(x0, s0, xbufB, s_f, s_b);

    for (int t = 0; t < T_; ++t){
        float* spf = s_f + (size_t)(t & 1)*(B_*HID_);
        float* snf = s_f + (size_t)((t & 1)^1)*(B_*HID_);
        k_gA  <<< 96, 512, 0, stream>>>(xb16, x, use_xb, Wcat, b, xbufB, s_b, spf,
                                        rs_b, pre_z, pre_xs, t);
        k_gB  <<< 32, 512, 0, stream>>>(Ust, rs_b, pre_z, pre_xs, spf, snf, s_b);
        k_gC  <<< 16, 512, 0, stream>>>(Wxt, s_b, bx, logits);
        k_soft<<<128, 256, 0, stream>>>(logits, Wy, by, xbufB, out, t);
    }
}